// Round 3
// baseline (509.298 us; speedup 1.0000x reference)
//
#include <hip/hip_runtime.h>

#define NTOK 16384
#define DIM  128
#define NJT  128   // number of 128-wide j tiles
#define RB   64    // i-rows per attn block

typedef __attribute__((ext_vector_type(8))) short short8;
typedef __attribute__((ext_vector_type(4))) float f32x4;

// fold 1/sqrt(128) * log2(e) into Q so scores come out in log2 domain
#define QSCALE (1.4426950408889634f * 0.08838834764831845f)

// barrier that drains LDS ops only -- global loads stay in flight
#define BAR() asm volatile("s_waitcnt lgkmcnt(0)\n\ts_barrier" ::: "memory")

__device__ __forceinline__ short f2bf(float f) {
  union { float f; unsigned u; } v; v.f = f;
  return (short)((v.u + 0x7FFFu + ((v.u >> 16) & 1u)) >> 16);
}

__device__ __forceinline__ short8 pack8(const float4 a, const float4 b) {
  short8 r;
  r[0] = f2bf(a.x); r[1] = f2bf(a.y); r[2] = f2bf(a.z); r[3] = f2bf(a.w);
  r[4] = f2bf(b.x); r[5] = f2bf(b.y); r[6] = f2bf(b.z); r[7] = f2bf(b.w);
  return r;
}

// fragment-contiguous chunk offset: chunk (t, kf, lg, r) is 16 bytes
__device__ __forceinline__ int kvoff(int t, int kf, int lg, int r) {
  return ((((t * 4 + kf) * 4 + lg) * 128) + r) * 16;
}

// pls swizzle: keeps both b16 writes and b128 reads conflict-free/2-way
__device__ __forceinline__ int psw(int r) { return ((r >> 1) & 7) << 4; }

// ---------------------------------------------------------------------------
// Kernel 1: QKV projection.
//  Qb: [N][128] bf16 row-major, pre-scaled by QSCALE
//  K2: fragment-contiguous chunks; chunk(t,kf,lg,j) = K[t*128+j][kf*32+lg*8 .. +8]
//  V2: fragment-contiguous chunks; chunk(t,kf,lg,d) = V[t*128+kf*32+lg*8 .. +8][d]
// ---------------------------------------------------------------------------
__device__ __forceinline__ void mm16(const short8 (&af)[4], const float* __restrict__ W,
                                     const float* __restrict__ b, int l15, int lg,
                                     f32x4 (&acc)[8], float (&bias)[8]) {
#pragma unroll
  for (int nf = 0; nf < 8; ++nf) {
    acc[nf][0] = 0.f; acc[nf][1] = 0.f; acc[nf][2] = 0.f; acc[nf][3] = 0.f;
  }
#pragma unroll
  for (int kf = 0; kf < 4; ++kf) {
#pragma unroll
    for (int nf = 0; nf < 8; ++nf) {
      const float* wp = W + (size_t)(nf * 16 + l15) * DIM + kf * 32 + lg * 8;
      short8 bfr = pack8(*(const float4*)wp, *(const float4*)(wp + 4));
      acc[nf] = __builtin_amdgcn_mfma_f32_16x16x32_bf16(af[kf], bfr, acc[nf], 0, 0, 0);
    }
  }
#pragma unroll
  for (int nf = 0; nf < 8; ++nf) bias[nf] = b[nf * 16 + l15];
}

__global__ __launch_bounds__(256) void proj_kernel(
    const float* __restrict__ X,
    const float* __restrict__ Wq, const float* __restrict__ bq,
    const float* __restrict__ Wk, const float* __restrict__ bk,
    const float* __restrict__ Wv, const float* __restrict__ bv,
    short* __restrict__ Qb, char* __restrict__ K2, char* __restrict__ V2) {
  __shared__ short ktile[64][136];
  __shared__ short vtile[64][136];

  const int tid = threadIdx.x;
  const int w = tid >> 6, lane = tid & 63;
  const int l15 = lane & 15, lg = lane >> 4;
  const int i0 = blockIdx.x * 64;
  const int t = i0 >> 7, jl0 = i0 & 127;

  // A fragments from X (16 rows per wave)
  short8 af[4];
  {
    const int xrow = i0 + w * 16 + l15;
#pragma unroll
    for (int kf = 0; kf < 4; ++kf) {
      const float* xp = X + (size_t)xrow * DIM + kf * 32 + lg * 8;
      af[kf] = pack8(*(const float4*)xp, *(const float4*)(xp + 4));
    }
  }

  f32x4 acc[8];
  float bias[8];

  // ---- Q ----
  mm16(af, Wq, bq, l15, lg, acc, bias);
#pragma unroll
  for (int nf = 0; nf < 8; ++nf) {
    const int d = nf * 16 + l15;
#pragma unroll
    for (int rr = 0; rr < 4; ++rr) {
      const int i = i0 + w * 16 + lg * 4 + rr;
      Qb[(size_t)i * DIM + d] = f2bf((acc[nf][rr] + bias[nf]) * QSCALE);
    }
  }

  // ---- K ----
  mm16(af, Wk, bk, l15, lg, acc, bias);
#pragma unroll
  for (int nf = 0; nf < 8; ++nf) {
    const int d = nf * 16 + l15;
#pragma unroll
    for (int rr = 0; rr < 4; ++rr)
      ktile[w * 16 + lg * 4 + rr][d] = f2bf(acc[nf][rr] + bias[nf]);
  }

  // ---- V ----
  mm16(af, Wv, bv, l15, lg, acc, bias);
#pragma unroll
  for (int nf = 0; nf < 8; ++nf) {
    const int d = nf * 16 + l15;
#pragma unroll
    for (int rr = 0; rr < 4; ++rr)
      vtile[w * 16 + lg * 4 + rr][d] = f2bf(acc[nf][rr] + bias[nf]);
  }
  __syncthreads();

  // K chunks: task = octet o (16) x local row (64)
#pragma unroll
  for (int it = 0; it < 4; ++it) {
    const int task = it * 256 + tid;
    const int o = task >> 6, jr = task & 63;
    const int kf = o >> 2, lg2 = o & 3;
    short8 st = *(const short8*)&ktile[jr][o * 8];
    *(short8*)(K2 + kvoff(t, kf, lg2, jl0 + jr)) = st;
  }

  // V chunks: task = c (8 j-octets) x d (128)
#pragma unroll
  for (int it = 0; it < 4; ++it) {
    const int task = it * 256 + tid;
    const int c = task >> 7, d = task & 127;
    short8 st;
#pragma unroll
    for (int s2 = 0; s2 < 8; ++s2) st[s2] = vtile[c * 8 + s2][d];
    const int jl = jl0 + c * 8;
    const int kf = jl >> 5, lg2 = (jl >> 3) & 3;
    *(short8*)(V2 + kvoff(t, kf, lg2, d)) = st;
  }
}

// ---------------------------------------------------------------------------
// Kernel 2: fused masked-softmax attention.
// 256 blocks x 512 threads (8 waves). Block owns 64 i-rows.
// wave (ir,wc): i-half [ir*32,+32), j/d-slice [wc*32,+32).
// K register-double-buffered (prefetched 1 tile ahead); V prefetched before
// exp2 phase; adj prefetched 1 tile ahead; P double-buffered in LDS -> one
// barrier per step. K/V read directly from L2/L3 (fragment-contiguous).
// ---------------------------------------------------------------------------
__device__ __forceinline__ void load_adj(int (&dst)[2][4][2], const int* __restrict__ adj,
                                         int tt, int i0, int ir, int wc, int l15, int lg) {
#pragma unroll
  for (int mf = 0; mf < 2; ++mf) {
#pragma unroll
    for (int rr = 0; rr < 4; ++rr) {
      const size_t row = (size_t)(i0 + ir * 32 + mf * 16 + lg * 4 + rr);
      const int* ap = adj + row * NTOK + tt * 128 + wc * 32 + l15;
      dst[mf][rr][0] = ap[0];
      dst[mf][rr][1] = ap[16];
    }
  }
}

__device__ __forceinline__ void load_kfrag(short8 (&k)[4][2], const char* __restrict__ K2,
                                           int t, int wc, int l15, int lg) {
#pragma unroll
  for (int kf = 0; kf < 4; ++kf)
#pragma unroll
    for (int nf = 0; nf < 2; ++nf) {
      const int jl = wc * 32 + nf * 16 + l15;
      k[kf][nf] = *(const short8*)(K2 + kvoff(t, kf, lg, jl));
    }
}

__device__ __forceinline__ void attn_step(
    int t, const char* __restrict__ K2, const char* __restrict__ V2,
    const int* __restrict__ adj, char* plsW, const char* plsR,
    const short8 (&qf)[2][4], const short8 (&kC)[4][2], short8 (&kN)[4][2],
    f32x4 (&acc)[2][2], float (&dsum)[8],
    int (&adjC)[2][4][2], int (&adjN)[2][4][2],
    int i0, int ir, int wc, int l15, int lg) {
  const int tn = (t + 1) & (NJT - 1);

  // ---- S = Q @ K^T (K fragments already in registers) ----
  f32x4 s[2][2];
#pragma unroll
  for (int mf = 0; mf < 2; ++mf)
#pragma unroll
    for (int nf = 0; nf < 2; ++nf) {
      s[mf][nf][0] = 0.f; s[mf][nf][1] = 0.f; s[mf][nf][2] = 0.f; s[mf][nf][3] = 0.f;
    }
#pragma unroll
  for (int kf = 0; kf < 4; ++kf)
#pragma unroll
    for (int nf = 0; nf < 2; ++nf)
#pragma unroll
      for (int mf = 0; mf < 2; ++mf)
        s[mf][nf] = __builtin_amdgcn_mfma_f32_16x16x32_bf16(qf[mf][kf], kC[kf][nf], s[mf][nf], 0, 0, 0);

  // prefetch next K tile fragments + next adj tile (consumed next step)
  load_kfrag(kN, K2, tn, wc, l15, lg);
  load_adj(adjN, adj, tn, i0, ir, wc, l15, lg);

  // V fragments for this tile (consumed after the barrier)
  short8 vf[4][2];
#pragma unroll
  for (int kf = 0; kf < 4; ++kf)
#pragma unroll
    for (int nf = 0; nf < 2; ++nf) {
      const int d = wc * 32 + nf * 16 + l15;
      vf[kf][nf] = *(const short8*)(V2 + kvoff(t, kf, lg, d));
    }

  // ---- P = exp2(adj ? s : 0); row-sum; write P to LDS (swizzled) ----
#pragma unroll
  for (int mf = 0; mf < 2; ++mf)
#pragma unroll
    for (int nf = 0; nf < 2; ++nf)
#pragma unroll
      for (int rr = 0; rr < 4; ++rr) {
        const float sv = adjC[mf][rr][nf] ? s[mf][nf][rr] : 0.0f;
        const float p = __builtin_exp2f(sv);
        dsum[mf * 4 + rr] += p;
        const int r = ir * 32 + mf * 16 + lg * 4 + rr;
        const int c = wc * 32 + nf * 16 + l15;
        *(short*)(plsW + ((r * 256 + c * 2) ^ psw(r))) = f2bf(p);
      }
  BAR();  // P(t) visible; LDS drain only, global loads stay in flight

  // ---- acc += P @ V ----
#pragma unroll
  for (int kf = 0; kf < 4; ++kf) {
    short8 pa[2];
#pragma unroll
    for (int mf = 0; mf < 2; ++mf) {
      const int row = ir * 32 + mf * 16 + l15;
      pa[mf] = *(const short8*)(plsW + ((row * 256 + (kf * 32 + lg * 8) * 2) ^ psw(row)));
    }
#pragma unroll
    for (int nf = 0; nf < 2; ++nf)
#pragma unroll
      for (int mf = 0; mf < 2; ++mf)
        acc[mf][nf] = __builtin_amdgcn_mfma_f32_16x16x32_bf16(pa[mf], vf[kf][nf], acc[mf][nf], 0, 0, 0);
  }
  // no trailing barrier: next step writes the OTHER pls buffer; the WAR on
  // this buffer is protected by the next step's barrier.
  (void)plsR;
}

__global__ __launch_bounds__(512, 2) void attn_kernel(
    const short* __restrict__ QbG, const char* __restrict__ K2,
    const char* __restrict__ V2, const int* __restrict__ adj,
    float* __restrict__ out) {
  __shared__ __align__(16) char pls[2][RB * 256];   // 2 x 16 KB
  __shared__ float denp[4][RB];

  const int tid = threadIdx.x;
  const int w = tid >> 6, lane = tid & 63;
  const int l15 = lane & 15, lg = lane >> 4;
  const int ir = w >> 2, wc = w & 3;
  const int i0 = blockIdx.x * RB;

  // Q fragments (persist in registers)
  short8 qf[2][4];
#pragma unroll
  for (int mf = 0; mf < 2; ++mf) {
    const int i = i0 + ir * 32 + mf * 16 + l15;
#pragma unroll
    for (int kf = 0; kf < 4; ++kf)
      qf[mf][kf] = *(const short8*)(QbG + (size_t)i * DIM + kf * 32 + lg * 8);
  }

  f32x4 acc[2][2];
#pragma unroll
  for (int mf = 0; mf < 2; ++mf)
#pragma unroll
    for (int nf = 0; nf < 2; ++nf) {
      acc[mf][nf][0] = 0.f; acc[mf][nf][1] = 0.f; acc[mf][nf][2] = 0.f; acc[mf][nf][3] = 0.f;
    }
  float dsum[8] = {0.f, 0.f, 0.f, 0.f, 0.f, 0.f, 0.f, 0.f};
  int adjA[2][4][2], adjB[2][4][2];
  short8 kA[4][2], kB[4][2];

  load_kfrag(kA, K2, 0, wc, l15, lg);
  load_adj(adjA, adj, 0, i0, ir, wc, l15, lg);

  for (int t = 0; t < NJT; t += 2) {
    attn_step(t,     K2, V2, adj, pls[0], pls[1], qf, kA, kB, acc, dsum,
              adjA, adjB, i0, ir, wc, l15, lg);
    attn_step(t + 1, K2, V2, adj, pls[1], pls[0], qf, kB, kA, acc, dsum,
              adjB, adjA, i0, ir, wc, l15, lg);
  }

  // deterministic denominator reduction over the 16 lanes of each l15-group
#pragma unroll
  for (int q = 0; q < 8; ++q) {
    float v = dsum[q];
    v += __shfl_xor(v, 1);
    v += __shfl_xor(v, 2);
    v += __shfl_xor(v, 4);
    v += __shfl_xor(v, 8);
    if (l15 == 0) {
      const int mf = q >> 2, rr = q & 3;
      denp[wc][ir * 32 + mf * 16 + lg * 4 + rr] = v;
    }
  }
  __syncthreads();

#pragma unroll
  for (int mf = 0; mf < 2; ++mf)
#pragma unroll
    for (int nf = 0; nf < 2; ++nf)
#pragma unroll
      for (int rr = 0; rr < 4; ++rr) {
        const int r = ir * 32 + mf * 16 + lg * 4 + rr;
        const float den = denp[0][r] + denp[1][r] + denp[2][r] + denp[3][r];
        out[(size_t)(i0 + r) * DIM + wc * 32 + nf * 16 + l15] = acc[mf][nf][rr] / den;
      }
}

// ---------------------------------------------------------------------------
extern "C" void kernel_launch(void* const* d_in, const int* in_sizes, int n_in,
                              void* d_out, int out_size, void* d_ws, size_t ws_size,
                              hipStream_t stream) {
  const float* X  = (const float*)d_in[0];
  const float* Wq = (const float*)d_in[1];
  const float* bq = (const float*)d_in[2];
  const float* Wk = (const float*)d_in[3];
  const float* bk = (const float*)d_in[4];
  const float* Wv = (const float*)d_in[5];
  const float* bv = (const float*)d_in[6];
  const int*  adj = (const int*)d_in[7];
  float* out = (float*)d_out;

  char* ws = (char*)d_ws;
  short* Qb = (short*)ws;                       // 4 MB bf16 [N][128]
  char*  K2 = ws + ((size_t)4 << 20);           // 4 MB fragment-contiguous K
  char*  V2 = ws + ((size_t)8 << 20);           // 4 MB fragment-contiguous V^T

  proj_kernel<<<256, 256, 0, stream>>>(X, Wq, bq, Wk, bk, Wv, bv, Qb, K2, V2);
  attn_kernel<<<NTOK / RB, 512, 0, stream>>>(Qb, K2, V2, adj, out);
}

// Round 4
// 437.735 us; speedup vs baseline: 1.1635x; 1.1635x over previous
//
#include <hip/hip_runtime.h>

#define NTOK 16384
#define DIM  128
#define NJT  128   // number of 128-wide j tiles

typedef __attribute__((ext_vector_type(8))) short short8;
typedef __attribute__((ext_vector_type(4))) float f32x4;
typedef __attribute__((ext_vector_type(4))) int   i32x4;

// fold 1/sqrt(128) * log2(e) into Q so scores come out in log2 domain
#define QSCALE (1.4426950408889634f * 0.08838834764831845f)

__device__ __forceinline__ short f2bf(float f) {
  union { float f; unsigned u; } v; v.f = f;
  return (short)((v.u + 0x7FFFu + ((v.u >> 16) & 1u)) >> 16);
}

__device__ __forceinline__ unsigned pkbf(float lo, float hi) {
  return ((unsigned)(unsigned short)f2bf(hi) << 16) | (unsigned short)f2bf(lo);
}

__device__ __forceinline__ short8 pack8(const float4 a, const float4 b) {
  short8 r;
  r[0] = f2bf(a.x); r[1] = f2bf(a.y); r[2] = f2bf(a.z); r[3] = f2bf(a.w);
  r[4] = f2bf(b.x); r[5] = f2bf(b.y); r[6] = f2bf(b.z); r[7] = f2bf(b.w);
  return r;
}

// V2 chunk offset: chunk (t, kf, lg, d) is 16 bytes
__device__ __forceinline__ int kvoff(int t, int kf, int lg, int r) {
  return ((((t * 4 + kf) * 4 + lg) * 128) + r) * 16;
}

// ---------------------------------------------------------------------------
// Kernel 1: QKV projection.
//  Qb: [N][128] bf16 row-major, pre-scaled by QSCALE
//  K3: A-frag-contiguous: chunk(t, jfg, kf) = 1KB; lane l (=l15+16*lg) holds
//      K[t*128 + jfg*16 + l15][kf*32 + lg*8 .. +8]
//  V2: B-frag-contiguous: chunk(t,kf,lg,d) = V[t*128+kf*32+lg*8 .. +8][d]
// ---------------------------------------------------------------------------
__device__ __forceinline__ void mm16(const short8 (&af)[4], const float* __restrict__ W,
                                     const float* __restrict__ b, int l15, int lg,
                                     f32x4 (&acc)[8], float (&bias)[8]) {
#pragma unroll
  for (int nf = 0; nf < 8; ++nf) {
    acc[nf][0] = 0.f; acc[nf][1] = 0.f; acc[nf][2] = 0.f; acc[nf][3] = 0.f;
  }
#pragma unroll
  for (int kf = 0; kf < 4; ++kf) {
#pragma unroll
    for (int nf = 0; nf < 8; ++nf) {
      const float* wp = W + (size_t)(nf * 16 + l15) * DIM + kf * 32 + lg * 8;
      short8 bfr = pack8(*(const float4*)wp, *(const float4*)(wp + 4));
      acc[nf] = __builtin_amdgcn_mfma_f32_16x16x32_bf16(af[kf], bfr, acc[nf], 0, 0, 0);
    }
  }
#pragma unroll
  for (int nf = 0; nf < 8; ++nf) bias[nf] = b[nf * 16 + l15];
}

__global__ __launch_bounds__(256) void proj_kernel(
    const float* __restrict__ X,
    const float* __restrict__ Wq, const float* __restrict__ bq,
    const float* __restrict__ Wk, const float* __restrict__ bk,
    const float* __restrict__ Wv, const float* __restrict__ bv,
    short* __restrict__ Qb, char* __restrict__ K3, char* __restrict__ V2) {
  __shared__ short ktile[64][136];
  __shared__ short vtile[64][136];

  const int tid = threadIdx.x;
  const int w = tid >> 6, lane = tid & 63;
  const int l15 = lane & 15, lg = lane >> 4;
  const int i0 = blockIdx.x * 64;
  const int t = i0 >> 7, jl0 = i0 & 127;

  short8 af[4];
  {
    const int xrow = i0 + w * 16 + l15;
#pragma unroll
    for (int kf = 0; kf < 4; ++kf) {
      const float* xp = X + (size_t)xrow * DIM + kf * 32 + lg * 8;
      af[kf] = pack8(*(const float4*)xp, *(const float4*)(xp + 4));
    }
  }

  f32x4 acc[8];
  float bias[8];

  // ---- Q ----
  mm16(af, Wq, bq, l15, lg, acc, bias);
#pragma unroll
  for (int nf = 0; nf < 8; ++nf) {
    const int d = nf * 16 + l15;
#pragma unroll
    for (int rr = 0; rr < 4; ++rr) {
      const int i = i0 + w * 16 + lg * 4 + rr;
      Qb[(size_t)i * DIM + d] = f2bf((acc[nf][rr] + bias[nf]) * QSCALE);
    }
  }

  // ---- K ----
  mm16(af, Wk, bk, l15, lg, acc, bias);
#pragma unroll
  for (int nf = 0; nf < 8; ++nf) {
    const int d = nf * 16 + l15;
#pragma unroll
    for (int rr = 0; rr < 4; ++rr)
      ktile[w * 16 + lg * 4 + rr][d] = f2bf(acc[nf][rr] + bias[nf]);
  }

  // ---- V ----
  mm16(af, Wv, bv, l15, lg, acc, bias);
#pragma unroll
  for (int nf = 0; nf < 8; ++nf) {
    const int d = nf * 16 + l15;
#pragma unroll
    for (int rr = 0; rr < 4; ++rr)
      vtile[w * 16 + lg * 4 + rr][d] = f2bf(acc[nf][rr] + bias[nf]);
  }
  __syncthreads();

  // K3 chunks: task = chunk o (0..15) x local row (0..63)
#pragma unroll
  for (int it = 0; it < 4; ++it) {
    const int task = it * 256 + tid;
    const int o = task >> 6, jr = task & 63;
    const int j = i0 + jr;
    const int jfg = (j >> 4) & 7;
    const int kf = o >> 2, lgc = o & 3;
    short8 st = *(const short8*)&ktile[jr][o * 8];
    *(short8*)(K3 + ((size_t)((t * 8 + jfg) * 4 + kf) << 10) + lgc * 256 + (j & 15) * 16) = st;
  }

  // V2 chunks: task = c (8 j-octets) x d (128)
#pragma unroll
  for (int it = 0; it < 4; ++it) {
    const int task = it * 256 + tid;
    const int c = task >> 7, d = task & 127;
    short8 st;
#pragma unroll
    for (int s2 = 0; s2 < 8; ++s2) st[s2] = vtile[c * 8 + s2][d];
    const int jl = jl0 + c * 8;
    const int kf = jl >> 5, lg2 = (jl >> 3) & 3;
    *(short8*)(V2 + kvoff(t, kf, lg2, d)) = st;
  }
}

// ---------------------------------------------------------------------------
// Kernel 2: fused masked-softmax attention, swapped-QK^T, barrier-free loop.
// 256 blocks x 512 threads (8 waves). Block owns 64 i-rows.
// Wave (ir, wc): i-rows [ir*32,+32), j-slice [wc*32,+32) of every tile.
// Per step: S^T = mfma(K,Q) -> in-register mask/exp2/pack -> bpermute
// exchange -> PV partial (d:128). Cross-wave j-sum in LDS epilogue.
// ---------------------------------------------------------------------------
__device__ __forceinline__ void load_k(short8 (&k)[2][4], const char* __restrict__ K3,
                                       int t, int wc, int lane) {
#pragma unroll
  for (int jf = 0; jf < 2; ++jf)
#pragma unroll
    for (int kf = 0; kf < 4; ++kf)
      k[jf][kf] = *(const short8*)(K3 + ((size_t)((t * 8 + wc * 2 + jf) * 4 + kf) << 10) + lane * 16);
}

__device__ __forceinline__ void load_v(short8 (&v)[8], const char* __restrict__ V2,
                                       int t, int wc, int l15, int lg) {
#pragma unroll
  for (int nf = 0; nf < 8; ++nf)
    v[nf] = *(const short8*)(V2 + kvoff(t, wc, lg, nf * 16 + l15));
}

__device__ __forceinline__ void load_adj(i32x4 (&a)[2][2], const int* __restrict__ adj,
                                         int t, int i0, int ir, int wc, int l15, int lg) {
#pragma unroll
  for (int f = 0; f < 2; ++f)
#pragma unroll
    for (int jf = 0; jf < 2; ++jf) {
      const size_t row = (size_t)(i0 + ir * 32 + f * 16 + l15);
      a[f][jf] = *(const i32x4*)(adj + row * NTOK + t * 128 + wc * 32 + jf * 16 + lg * 4);
    }
}

__device__ __forceinline__ void attn_step(
    int t, const char* __restrict__ K3, const char* __restrict__ V2,
    const int* __restrict__ adj,
    const short8 (&qf)[2][4], short8 (&kfr)[2][4], short8 (&vfr)[8],
    f32x4 (&acc)[2][8], float (&dsum)[2],
    const i32x4 (&adjC)[2][2], i32x4 (&adjN)[2][2],
    int i0, int ir, int wc, int l15, int lg, int lane, int adA, int adB, bool hi5) {
  const int tn = (t + 1) & (NJT - 1);

  // adj for t+1: longest slack (consumed mid-next-step, HBM latency)
  load_adj(adjN, adj, tn, i0, ir, wc, l15, lg);

  // ---- S^T = K @ Q^T : lane holds S[i=l15][j=lg*4+r] per (f,jf) ----
  f32x4 sT[2][2];
#pragma unroll
  for (int f = 0; f < 2; ++f)
#pragma unroll
    for (int jf = 0; jf < 2; ++jf) {
      sT[f][jf][0] = 0.f; sT[f][jf][1] = 0.f; sT[f][jf][2] = 0.f; sT[f][jf][3] = 0.f;
    }
#pragma unroll
  for (int kf = 0; kf < 4; ++kf)
#pragma unroll
    for (int jf = 0; jf < 2; ++jf)
#pragma unroll
      for (int f = 0; f < 2; ++f)
        sT[f][jf] = __builtin_amdgcn_mfma_f32_16x16x32_bf16(kfr[jf][kf], qf[f][kf], sT[f][jf], 0, 0, 0);

  // reload K for t+1 (consumed at next step's QK; ~full step of slack)
  load_k(kfr, K3, tn, wc, lane);

  // ---- mask + exp2 + row-sum + pack to bf16 pairs, all in-register ----
  unsigned pk_[2][2][2];
#pragma unroll
  for (int f = 0; f < 2; ++f)
#pragma unroll
    for (int jf = 0; jf < 2; ++jf) {
      const i32x4 a = adjC[f][jf];
      float p0 = __builtin_exp2f(a[0] ? sT[f][jf][0] : 0.0f);
      float p1 = __builtin_exp2f(a[1] ? sT[f][jf][1] : 0.0f);
      float p2 = __builtin_exp2f(a[2] ? sT[f][jf][2] : 0.0f);
      float p3 = __builtin_exp2f(a[3] ? sT[f][jf][3] : 0.0f);
      dsum[f] += (p0 + p1) + (p2 + p3);
      pk_[f][jf][0] = pkbf(p0, p1);
      pk_[f][jf][1] = pkbf(p2, p3);
    }

  // ---- in-wave exchange: build PV A-frags (P[i=l15][j=lg*8+e]) ----
  i32x4 pa[2];
#pragma unroll
  for (int f = 0; f < 2; ++f)
#pragma unroll
    for (int w2 = 0; w2 < 4; ++w2) {
      const int addr = (w2 < 2) ? adA : adB;
      int r0 = __builtin_amdgcn_ds_bpermute(addr, (int)pk_[f][0][w2 & 1]);
      int r1 = __builtin_amdgcn_ds_bpermute(addr, (int)pk_[f][1][w2 & 1]);
      pa[f][w2] = hi5 ? r1 : r0;
    }

  // ---- acc += P @ V (partial over this wave's j:32, full d:128) ----
#pragma unroll
  for (int nf = 0; nf < 8; ++nf) {
    const short8 vb = vfr[nf];
#pragma unroll
    for (int f = 0; f < 2; ++f) {
      const short8 pab = *(const short8*)&pa[f];
      acc[f][nf] = __builtin_amdgcn_mfma_f32_16x16x32_bf16(pab, vb, acc[f][nf], 0, 0, 0);
    }
  }

  // reload V for t+1 (consumed at next step's PV)
  load_v(vfr, V2, tn, wc, l15, lg);
}

__global__ __launch_bounds__(512, 2) void attn_kernel(
    const short* __restrict__ QbG, const char* __restrict__ K3,
    const char* __restrict__ V2, const int* __restrict__ adj,
    float* __restrict__ out) {
  __shared__ float red[2][32][132];   // ~33.8 KB, padded (2-way = free)
  __shared__ float denp[4][64];

  const int tid = threadIdx.x;
  const int w = tid >> 6, lane = tid & 63;
  const int l15 = lane & 15, lg = lane >> 4;
  const int ir = w >> 2, wc = w & 3;
  const int i0 = blockIdx.x * 64;

  // bpermute source-lane addresses (h = w2>>1), jf-select by lane bit5
  const int adA = 4 * (l15 + 16 * ((lg & 1) * 2 + 0));
  const int adB = 4 * (l15 + 16 * ((lg & 1) * 2 + 1));
  const bool hi5 = (lane & 32) != 0;

  // Q B-frags (persist)
  short8 qf[2][4];
#pragma unroll
  for (int f = 0; f < 2; ++f) {
    const int i = i0 + ir * 32 + f * 16 + l15;
#pragma unroll
    for (int kf = 0; kf < 4; ++kf)
      qf[f][kf] = *(const short8*)(QbG + (size_t)i * DIM + kf * 32 + lg * 8);
  }

  f32x4 acc[2][8];
#pragma unroll
  for (int f = 0; f < 2; ++f)
#pragma unroll
    for (int nf = 0; nf < 8; ++nf) {
      acc[f][nf][0] = 0.f; acc[f][nf][1] = 0.f; acc[f][nf][2] = 0.f; acc[f][nf][3] = 0.f;
    }
  float dsum[2] = {0.f, 0.f};

  short8 kfr[2][4];
  short8 vfr[8];
  i32x4 adjA_[2][2], adjB_[2][2];

  load_k(kfr, K3, 0, wc, lane);
  load_v(vfr, V2, 0, wc, l15, lg);
  load_adj(adjA_, adj, 0, i0, ir, wc, l15, lg);

  for (int t = 0; t < NJT; t += 2) {
    attn_step(t,     K3, V2, adj, qf, kfr, vfr, acc, dsum, adjA_, adjB_,
              i0, ir, wc, l15, lg, lane, adA, adB, hi5);
    attn_step(t + 1, K3, V2, adj, qf, kfr, vfr, acc, dsum, adjB_, adjA_,
              i0, ir, wc, l15, lg, lane, adA, adB, hi5);
  }

  // ---- denominator: reduce over lg groups (j), then across wc waves ----
  float d0 = dsum[0], d1 = dsum[1];
  d0 += __shfl_xor(d0, 16); d0 += __shfl_xor(d0, 32);
  d1 += __shfl_xor(d1, 16); d1 += __shfl_xor(d1, 32);
  if (lg == 0) {
    denp[wc][ir * 32 + l15] = d0;
    denp[wc][ir * 32 + 16 + l15] = d1;
  }
  __syncthreads();
  if (tid < 64)
    denp[0][tid] = (denp[0][tid] + denp[1][tid]) + (denp[2][tid] + denp[3][tid]);

  // ---- cross-wave acc reduction: 3 rounds through red[ir] ----
#pragma unroll
  for (int rnd = 1; rnd <= 3; ++rnd) {
    __syncthreads();
    if (wc == rnd) {
#pragma unroll
      for (int f = 0; f < 2; ++f)
#pragma unroll
        for (int nf = 0; nf < 8; ++nf)
#pragma unroll
          for (int r = 0; r < 4; ++r)
            red[ir][f * 16 + lg * 4 + r][nf * 16 + l15] = acc[f][nf][r];
    }
    __syncthreads();
    if (wc == 0) {
#pragma unroll
      for (int f = 0; f < 2; ++f)
#pragma unroll
        for (int nf = 0; nf < 8; ++nf)
#pragma unroll
          for (int r = 0; r < 4; ++r)
            acc[f][nf][r] += red[ir][f * 16 + lg * 4 + r][nf * 16 + l15];
    }
  }

  if (wc == 0) {
    float dd[2][4];
#pragma unroll
    for (int f = 0; f < 2; ++f)
#pragma unroll
      for (int r = 0; r < 4; ++r)
        dd[f][r] = denp[0][ir * 32 + f * 16 + lg * 4 + r];
#pragma unroll
    for (int f = 0; f < 2; ++f)
#pragma unroll
      for (int nf = 0; nf < 8; ++nf)
#pragma unroll
        for (int r = 0; r < 4; ++r) {
          const int i = ir * 32 + f * 16 + lg * 4 + r;
          out[(size_t)(i0 + i) * DIM + nf * 16 + l15] = acc[f][nf][r] / dd[f][r];
        }
  }
}

// ---------------------------------------------------------------------------
extern "C" void kernel_launch(void* const* d_in, const int* in_sizes, int n_in,
                              void* d_out, int out_size, void* d_ws, size_t ws_size,
                              hipStream_t stream) {
  const float* X  = (const float*)d_in[0];
  const float* Wq = (const float*)d_in[1];
  const float* bq = (const float*)d_in[2];
  const float* Wk = (const float*)d_in[3];
  const float* bk = (const float*)d_in[4];
  const float* Wv = (const float*)d_in[5];
  const float* bv = (const float*)d_in[6];
  const int*  adj = (const int*)d_in[7];
  float* out = (float*)d_out;

  char* ws = (char*)d_ws;
  short* Qb = (short*)ws;                       // 4 MB bf16 [N][128]
  char*  K3 = ws + ((size_t)4 << 20);           // 4 MB A-frag-contiguous K
  char*  V2 = ws + ((size_t)8 << 20);           // 4 MB B-frag-contiguous V^T

  proj_kernel<<<256, 256, 0, stream>>>(X, Wq, bq, Wk, bk, Wv, bv, Qb, K3, V2);
  attn_kernel<<<256, 512, 0, stream>>>(Qb, K3, V2, adj, out);
}

// Round 5
// 385.410 us; speedup vs baseline: 1.3214x; 1.1358x over previous
//
#include <hip/hip_runtime.h>

#define NTOK 16384
#define DIM  128
#define NJT  128   // number of 128-wide j tiles
#define RB   64    // i-rows per attn block

typedef __attribute__((ext_vector_type(8))) short short8;
typedef __attribute__((ext_vector_type(4))) float f32x4;
typedef __attribute__((ext_vector_type(4))) int   i32x4;
typedef __attribute__((address_space(1))) void void_g;
typedef __attribute__((address_space(3))) void void_l;

// fold 1/sqrt(128) * log2(e) into Q so scores come out in log2 domain
#define QSCALE (1.4426950408889634f * 0.08838834764831845f)

__device__ __forceinline__ short f2bf(float f) {
  union { float f; unsigned u; } v; v.f = f;
  return (short)((v.u + 0x7FFFu + ((v.u >> 16) & 1u)) >> 16);
}

__device__ __forceinline__ unsigned pkbf(float lo, float hi) {
  return ((unsigned)(unsigned short)f2bf(hi) << 16) | (unsigned short)f2bf(lo);
}

__device__ __forceinline__ short8 pack8(const float4 a, const float4 b) {
  short8 r;
  r[0] = f2bf(a.x); r[1] = f2bf(a.y); r[2] = f2bf(a.z); r[3] = f2bf(a.w);
  r[4] = f2bf(b.x); r[5] = f2bf(b.y); r[6] = f2bf(b.z); r[7] = f2bf(b.w);
  return r;
}

__device__ __forceinline__ void gload16(char* l, const char* g) {
  __builtin_amdgcn_global_load_lds((void_g*)g, (void_l*)l, 16, 0, 0);
}

// V2 chunk offset: chunk (t, kf, lg, d) is 16 bytes
__device__ __forceinline__ int kvoff(int t, int kf, int lg, int r) {
  return ((((t * 4 + kf) * 4 + lg) * 128) + r) * 16;
}

// ---------------------------------------------------------------------------
// Kernel 1: QKV projection.
//  Qb: [N][128] bf16 row-major, pre-scaled by QSCALE
//  K3: A-frag chunks, tile t = 32KB at t*32768; chunk(jfg,kf)=1KB; lane l
//      holds K[t*128 + jfg*16 + (l&15)][kf*32 + (l>>4)*8 .. +8] at lane*16
//  V2: B-frag chunks, tile t = 32KB; chunk(kf,lg,d) per kvoff
// ---------------------------------------------------------------------------
__device__ __forceinline__ void mm16(const short8 (&af)[4], const float* __restrict__ W,
                                     const float* __restrict__ b, int l15, int lg,
                                     f32x4 (&acc)[8], float (&bias)[8]) {
#pragma unroll
  for (int nf = 0; nf < 8; ++nf) {
    acc[nf][0] = 0.f; acc[nf][1] = 0.f; acc[nf][2] = 0.f; acc[nf][3] = 0.f;
  }
#pragma unroll
  for (int kf = 0; kf < 4; ++kf) {
#pragma unroll
    for (int nf = 0; nf < 8; ++nf) {
      const float* wp = W + (size_t)(nf * 16 + l15) * DIM + kf * 32 + lg * 8;
      short8 bfr = pack8(*(const float4*)wp, *(const float4*)(wp + 4));
      acc[nf] = __builtin_amdgcn_mfma_f32_16x16x32_bf16(af[kf], bfr, acc[nf], 0, 0, 0);
    }
  }
#pragma unroll
  for (int nf = 0; nf < 8; ++nf) bias[nf] = b[nf * 16 + l15];
}

__global__ __launch_bounds__(256) void proj_kernel(
    const float* __restrict__ X,
    const float* __restrict__ Wq, const float* __restrict__ bq,
    const float* __restrict__ Wk, const float* __restrict__ bk,
    const float* __restrict__ Wv, const float* __restrict__ bv,
    short* __restrict__ Qb, char* __restrict__ K3, char* __restrict__ V2) {
  __shared__ short ktile[64][136];
  __shared__ short vtile[64][136];

  const int tid = threadIdx.x;
  const int w = tid >> 6, lane = tid & 63;
  const int l15 = lane & 15, lg = lane >> 4;
  const int i0 = blockIdx.x * 64;
  const int t = i0 >> 7, jl0 = i0 & 127;

  short8 af[4];
  {
    const int xrow = i0 + w * 16 + l15;
#pragma unroll
    for (int kf = 0; kf < 4; ++kf) {
      const float* xp = X + (size_t)xrow * DIM + kf * 32 + lg * 8;
      af[kf] = pack8(*(const float4*)xp, *(const float4*)(xp + 4));
    }
  }

  f32x4 acc[8];
  float bias[8];

  // ---- Q ----
  mm16(af, Wq, bq, l15, lg, acc, bias);
#pragma unroll
  for (int nf = 0; nf < 8; ++nf) {
    const int d = nf * 16 + l15;
#pragma unroll
    for (int rr = 0; rr < 4; ++rr) {
      const int i = i0 + w * 16 + lg * 4 + rr;
      Qb[(size_t)i * DIM + d] = f2bf((acc[nf][rr] + bias[nf]) * QSCALE);
    }
  }

  // ---- K ----
  mm16(af, Wk, bk, l15, lg, acc, bias);
#pragma unroll
  for (int nf = 0; nf < 8; ++nf) {
    const int d = nf * 16 + l15;
#pragma unroll
    for (int rr = 0; rr < 4; ++rr)
      ktile[w * 16 + lg * 4 + rr][d] = f2bf(acc[nf][rr] + bias[nf]);
  }

  // ---- V ----
  mm16(af, Wv, bv, l15, lg, acc, bias);
#pragma unroll
  for (int nf = 0; nf < 8; ++nf) {
    const int d = nf * 16 + l15;
#pragma unroll
    for (int rr = 0; rr < 4; ++rr)
      vtile[w * 16 + lg * 4 + rr][d] = f2bf(acc[nf][rr] + bias[nf]);
  }
  __syncthreads();

  // K3 chunks: task = chunk o (0..15) x local row (0..63)
#pragma unroll
  for (int it = 0; it < 4; ++it) {
    const int task = it * 256 + tid;
    const int o = task >> 6, jr = task & 63;
    const int j = i0 + jr;
    const int jfg = (j >> 4) & 7;
    const int kf = o >> 2, lgc = o & 3;
    short8 st = *(const short8*)&ktile[jr][o * 8];
    *(short8*)(K3 + ((size_t)((t * 8 + jfg) * 4 + kf) << 10) + lgc * 256 + (j & 15) * 16) = st;
  }

  // V2 chunks: task = c (8 j-octets) x d (128)
#pragma unroll
  for (int it = 0; it < 4; ++it) {
    const int task = it * 256 + tid;
    const int c = task >> 7, d = task & 127;
    short8 st;
#pragma unroll
    for (int s2 = 0; s2 < 8; ++s2) st[s2] = vtile[c * 8 + s2][d];
    const int jl = jl0 + c * 8;
    const int kf = jl >> 5, lg2 = (jl >> 3) & 3;
    *(short8*)(V2 + kvoff(t, kf, lg2, d)) = st;
  }
}

// ---------------------------------------------------------------------------
// Kernel 2: fused masked-softmax attention.
// 256 blocks x 1024 threads (16 waves, 1 block/CU, 4 waves/SIMD at <=128 VGPR).
// Wave (ir, wc): i-rows [ir*16,+16), j-slice [wc*32,+32).
// K/V double-buffered in LDS via global_load_lds; one barrier per step;
// softmax fully in-register (swapped QK^T + bpermute exchange).
// ---------------------------------------------------------------------------
__device__ __forceinline__ void stage_kv(char* dst, const char* __restrict__ K3,
                                         const char* __restrict__ V2, int t, int tid) {
  const char* gk = K3 + ((size_t)t << 15);
  const char* gv = V2 + ((size_t)t << 15);
  const int o = tid * 16;
  gload16(dst + o,         gk + o);
  gload16(dst + 16384 + o, gk + 16384 + o);
  gload16(dst + 32768 + o, gv + o);
  gload16(dst + 49152 + o, gv + 16384 + o);
}

__device__ __forceinline__ void load_adj(i32x4 (&a)[2], const int* __restrict__ adj,
                                         int t, int i0, int ir, int wc, int l15, int lg) {
  const int* ap = adj + (size_t)(i0 + ir * 16 + l15) * NTOK + t * 128 + wc * 32 + lg * 4;
  a[0] = *(const i32x4*)ap;
  a[1] = *(const i32x4*)(ap + 16);
}

__device__ __forceinline__ void attn_step(
    int t, const char* cur, char* nxt,
    const char* __restrict__ K3, const char* __restrict__ V2,
    const int* __restrict__ adj,
    const short8 (&qf)[4], f32x4 (&acc)[8], float& dsum,
    const i32x4 (&adjC)[2], i32x4 (&adjN)[2],
    int i0, int ir, int wc, int l15, int lg, int lane, int tid,
    int adA, int adB, bool hi5) {
  const int tn = (t + 1) & (NJT - 1);

  // stage next K/V tile into the other LDS buffer; prefetch next adj to regs
  stage_kv(nxt, K3, V2, tn, tid);
  load_adj(adjN, adj, tn, i0, ir, wc, l15, lg);

  // ---- S^T = K @ Q^T : lane holds S[i=l15][j=(wc*2+jf)*16 + lg*4+r] ----
  f32x4 sT[2];
#pragma unroll
  for (int jf = 0; jf < 2; ++jf) {
    sT[jf][0] = 0.f; sT[jf][1] = 0.f; sT[jf][2] = 0.f; sT[jf][3] = 0.f;
  }
#pragma unroll
  for (int jf = 0; jf < 2; ++jf)
#pragma unroll
    for (int kf = 0; kf < 4; ++kf) {
      const short8 kfr = *(const short8*)(cur + (((wc * 2 + jf) * 4 + kf) << 10) + lane * 16);
      sT[jf] = __builtin_amdgcn_mfma_f32_16x16x32_bf16(kfr, qf[kf], sT[jf], 0, 0, 0);
    }

  // ---- mask + exp2 + row-sum + pack, all in-register ----
  unsigned pk_[2][2];
#pragma unroll
  for (int jf = 0; jf < 2; ++jf) {
    const i32x4 a = adjC[jf];
    const float p0 = __builtin_exp2f(a[0] ? sT[jf][0] : 0.0f);
    const float p1 = __builtin_exp2f(a[1] ? sT[jf][1] : 0.0f);
    const float p2 = __builtin_exp2f(a[2] ? sT[jf][2] : 0.0f);
    const float p3 = __builtin_exp2f(a[3] ? sT[jf][3] : 0.0f);
    dsum += (p0 + p1) + (p2 + p3);
    pk_[jf][0] = pkbf(p0, p1);
    pk_[jf][1] = pkbf(p2, p3);
  }

  // ---- in-wave exchange: build PV A-frag P[i=l15][j=lg*8+e] ----
  i32x4 pa;
#pragma unroll
  for (int w2 = 0; w2 < 4; ++w2) {
    const int addr = (w2 < 2) ? adA : adB;
    const int r0 = __builtin_amdgcn_ds_bpermute(addr, (int)pk_[0][w2 & 1]);
    const int r1 = __builtin_amdgcn_ds_bpermute(addr, (int)pk_[1][w2 & 1]);
    pa[w2] = hi5 ? r1 : r0;
  }
  const short8 pa8 = *(const short8*)&pa;

  // ---- acc += P @ V (this wave's j:32, full d:128) ----
#pragma unroll
  for (int nf = 0; nf < 8; ++nf) {
    const short8 vb = *(const short8*)(cur + 32768 + ((((wc * 4 + lg) * 128) + nf * 16 + l15) << 4));
    acc[nf] = __builtin_amdgcn_mfma_f32_16x16x32_bf16(pa8, vb, acc[nf], 0, 0, 0);
  }

  // vmcnt(0)+lgkmcnt(0)+barrier: stage complete, buffers flip
  __syncthreads();
}

__global__ __launch_bounds__(1024, 4) void attn_kernel(
    const short* __restrict__ QbG, const char* __restrict__ K3,
    const char* __restrict__ V2, const int* __restrict__ adj,
    float* __restrict__ out) {
  __shared__ __align__(16) char kv[2][65536];   // [buf][ K:32KB | V:32KB ]
  __shared__ float denp[4][64];

  const int tid = threadIdx.x;
  const int w = tid >> 6, lane = tid & 63;
  const int l15 = lane & 15, lg = lane >> 4;
  const int ir = w >> 2, wc = w & 3;
  const int i0 = blockIdx.x * RB;

  // bpermute source-lane addresses; jf-select by lane bit 5
  const int adA = 4 * (l15 + 16 * ((lg & 1) * 2));
  const int adB = adA + 64;
  const bool hi5 = (lane & 32) != 0;

  // Q B-frags (persist): lane holds Q[i = i0+ir*16+l15][kf*32+lg*8 ..+8]
  short8 qf[4];
  {
    const int i = i0 + ir * 16 + l15;
#pragma unroll
    for (int kf = 0; kf < 4; ++kf)
      qf[kf] = *(const short8*)(QbG + (size_t)i * DIM + kf * 32 + lg * 8);
  }

  f32x4 acc[8];
#pragma unroll
  for (int nf = 0; nf < 8; ++nf) {
    acc[nf][0] = 0.f; acc[nf][1] = 0.f; acc[nf][2] = 0.f; acc[nf][3] = 0.f;
  }
  float dsum = 0.f;
  i32x4 adjA_[2], adjB_[2];

  stage_kv(kv[0], K3, V2, 0, tid);
  load_adj(adjA_, adj, 0, i0, ir, wc, l15, lg);
  __syncthreads();

  for (int t = 0; t < NJT; t += 2) {
    attn_step(t,     kv[0], kv[1], K3, V2, adj, qf, acc, dsum, adjA_, adjB_,
              i0, ir, wc, l15, lg, lane, tid, adA, adB, hi5);
    attn_step(t + 1, kv[1], kv[0], K3, V2, adj, qf, acc, dsum, adjB_, adjA_,
              i0, ir, wc, l15, lg, lane, tid, adA, adB, hi5);
  }

  // ---- denominator: lane covers i=l15; sum over lg groups, then wc ----
  float d0 = dsum;
  d0 += __shfl_xor(d0, 16);
  d0 += __shfl_xor(d0, 32);
  if (lg == 0) denp[wc][ir * 16 + l15] = d0;

  // ---- cross-wc acc reduction through LDS (reuse staging buffers) ----
  float* red = (float*)kv;   // 12 slots x 16 rows x 132 floats = 99 KB
  if (wc != 0) {
    const int base = ((wc - 1) * 4 + ir) * 16 * 132;
#pragma unroll
    for (int nf = 0; nf < 8; ++nf)
#pragma unroll
      for (int r = 0; r < 4; ++r)
        red[base + (lg * 4 + r) * 132 + nf * 16 + l15] = acc[nf][r];
  }
  __syncthreads();

  if (wc == 0) {
#pragma unroll
    for (int s = 0; s < 3; ++s) {
      const int base = (s * 4 + ir) * 16 * 132;
#pragma unroll
      for (int nf = 0; nf < 8; ++nf)
#pragma unroll
        for (int r = 0; r < 4; ++r)
          acc[nf][r] += red[base + (lg * 4 + r) * 132 + nf * 16 + l15];
    }
    float den[4];
#pragma unroll
    for (int r = 0; r < 4; ++r) {
      const int il = ir * 16 + lg * 4 + r;
      den[r] = (denp[0][il] + denp[1][il]) + (denp[2][il] + denp[3][il]);
    }
#pragma unroll
    for (int nf = 0; nf < 8; ++nf)
#pragma unroll
      for (int r = 0; r < 4; ++r) {
        const int i = ir * 16 + lg * 4 + r;
        out[(size_t)(i0 + i) * DIM + nf * 16 + l15] = acc[nf][r] / den[r];
      }
  }
}

// ---------------------------------------------------------------------------
extern "C" void kernel_launch(void* const* d_in, const int* in_sizes, int n_in,
                              void* d_out, int out_size, void* d_ws, size_t ws_size,
                              hipStream_t stream) {
  const float* X  = (const float*)d_in[0];
  const float* Wq = (const float*)d_in[1];
  const float* bq = (const float*)d_in[2];
  const float* Wk = (const float*)d_in[3];
  const float* bk = (const float*)d_in[4];
  const float* Wv = (const float*)d_in[5];
  const float* bv = (const float*)d_in[6];
  const int*  adj = (const int*)d_in[7];
  float* out = (float*)d_out;

  char* ws = (char*)d_ws;
  short* Qb = (short*)ws;                       // 4 MB bf16 [N][128]
  char*  K3 = ws + ((size_t)4 << 20);           // 4 MB A-frag-contiguous K
  char*  V2 = ws + ((size_t)8 << 20);           // 4 MB B-frag-contiguous V^T

  proj_kernel<<<256, 256, 0, stream>>>(X, Wq, bq, Wk, bk, Wv, bv, Qb, K3, V2);
  attn_kernel<<<256, 1024, 0, stream>>>(Qb, K3, V2, adj, out);
}

// Round 6
// 384.545 us; speedup vs baseline: 1.3244x; 1.0022x over previous
//
#include <hip/hip_runtime.h>

#define NTOK 16384
#define DIM  128
#define NJT  128   // number of 128-wide j tiles
#define RB   64    // i-rows per attn block

typedef __attribute__((ext_vector_type(8))) short short8;
typedef __attribute__((ext_vector_type(4))) float f32x4;
typedef __attribute__((ext_vector_type(4))) int   i32x4;
typedef __attribute__((address_space(1))) void void_g;
typedef __attribute__((address_space(3))) void void_l;

// fold 1/sqrt(128) * log2(e) into Q so scores come out in log2 domain
#define QSCALE (1.4426950408889634f * 0.08838834764831845f)

__device__ __forceinline__ short f2bf(float f) {
  union { float f; unsigned u; } v; v.f = f;
  return (short)((v.u + 0x7FFFu + ((v.u >> 16) & 1u)) >> 16);
}

__device__ __forceinline__ unsigned pkbf(float lo, float hi) {
  return ((unsigned)(unsigned short)f2bf(hi) << 16) | (unsigned short)f2bf(lo);
}

__device__ __forceinline__ short8 pack8(const float4 a, const float4 b) {
  short8 r;
  r[0] = f2bf(a.x); r[1] = f2bf(a.y); r[2] = f2bf(a.z); r[3] = f2bf(a.w);
  r[4] = f2bf(b.x); r[5] = f2bf(b.y); r[6] = f2bf(b.z); r[7] = f2bf(b.w);
  return r;
}

__device__ __forceinline__ void gload16(char* l, const char* g) {
  __builtin_amdgcn_global_load_lds((void_g*)g, (void_l*)l, 16, 0, 0);
}

// V2 chunk offset: chunk (t, kf, lg, d) is 16 bytes
__device__ __forceinline__ int kvoff(int t, int kf, int lg, int r) {
  return ((((t * 4 + kf) * 4 + lg) * 128) + r) * 16;
}

// ---------------------------------------------------------------------------
// Kernel 1: QKV projection.
//  Qb: [N][128] bf16 row-major, pre-scaled by QSCALE
//  K3: A-frag chunks, tile t = 32KB at t*32768; chunk(jfg,kf)=1KB; lane l
//      holds K[t*128 + jfg*16 + (l&15)][kf*32 + (l>>4)*8 .. +8] at lane*16
//  V2: B-frag chunks, tile t = 32KB; chunk(kf,lg,d) per kvoff
// ---------------------------------------------------------------------------
__device__ __forceinline__ void mm16(const short8 (&af)[4], const float* __restrict__ W,
                                     const float* __restrict__ b, int l15, int lg,
                                     f32x4 (&acc)[8], float (&bias)[8]) {
#pragma unroll
  for (int nf = 0; nf < 8; ++nf) {
    acc[nf][0] = 0.f; acc[nf][1] = 0.f; acc[nf][2] = 0.f; acc[nf][3] = 0.f;
  }
#pragma unroll
  for (int kf = 0; kf < 4; ++kf) {
#pragma unroll
    for (int nf = 0; nf < 8; ++nf) {
      const float* wp = W + (size_t)(nf * 16 + l15) * DIM + kf * 32 + lg * 8;
      short8 bfr = pack8(*(const float4*)wp, *(const float4*)(wp + 4));
      acc[nf] = __builtin_amdgcn_mfma_f32_16x16x32_bf16(af[kf], bfr, acc[nf], 0, 0, 0);
    }
  }
#pragma unroll
  for (int nf = 0; nf < 8; ++nf) bias[nf] = b[nf * 16 + l15];
}

__global__ __launch_bounds__(256) void proj_kernel(
    const float* __restrict__ X,
    const float* __restrict__ Wq, const float* __restrict__ bq,
    const float* __restrict__ Wk, const float* __restrict__ bk,
    const float* __restrict__ Wv, const float* __restrict__ bv,
    short* __restrict__ Qb, char* __restrict__ K3, char* __restrict__ V2) {
  __shared__ short ktile[64][136];
  __shared__ short vtile[64][136];

  const int tid = threadIdx.x;
  const int w = tid >> 6, lane = tid & 63;
  const int l15 = lane & 15, lg = lane >> 4;
  const int i0 = blockIdx.x * 64;
  const int t = i0 >> 7, jl0 = i0 & 127;

  short8 af[4];
  {
    const int xrow = i0 + w * 16 + l15;
#pragma unroll
    for (int kf = 0; kf < 4; ++kf) {
      const float* xp = X + (size_t)xrow * DIM + kf * 32 + lg * 8;
      af[kf] = pack8(*(const float4*)xp, *(const float4*)(xp + 4));
    }
  }

  f32x4 acc[8];
  float bias[8];

  // ---- Q ----
  mm16(af, Wq, bq, l15, lg, acc, bias);
#pragma unroll
  for (int nf = 0; nf < 8; ++nf) {
    const int d = nf * 16 + l15;
#pragma unroll
    for (int rr = 0; rr < 4; ++rr) {
      const int i = i0 + w * 16 + lg * 4 + rr;
      Qb[(size_t)i * DIM + d] = f2bf((acc[nf][rr] + bias[nf]) * QSCALE);
    }
  }

  // ---- K ----
  mm16(af, Wk, bk, l15, lg, acc, bias);
#pragma unroll
  for (int nf = 0; nf < 8; ++nf) {
    const int d = nf * 16 + l15;
#pragma unroll
    for (int rr = 0; rr < 4; ++rr)
      ktile[w * 16 + lg * 4 + rr][d] = f2bf(acc[nf][rr] + bias[nf]);
  }

  // ---- V ----
  mm16(af, Wv, bv, l15, lg, acc, bias);
#pragma unroll
  for (int nf = 0; nf < 8; ++nf) {
    const int d = nf * 16 + l15;
#pragma unroll
    for (int rr = 0; rr < 4; ++rr)
      vtile[w * 16 + lg * 4 + rr][d] = f2bf(acc[nf][rr] + bias[nf]);
  }
  __syncthreads();

  // K3 chunks: task = chunk o (0..15) x local row (0..63)
#pragma unroll
  for (int it = 0; it < 4; ++it) {
    const int task = it * 256 + tid;
    const int o = task >> 6, jr = task & 63;
    const int j = i0 + jr;
    const int jfg = (j >> 4) & 7;
    const int kf = o >> 2, lgc = o & 3;
    short8 st = *(const short8*)&ktile[jr][o * 8];
    *(short8*)(K3 + ((size_t)((t * 8 + jfg) * 4 + kf) << 10) + lgc * 256 + (j & 15) * 16) = st;
  }

  // V2 chunks: task = c (8 j-octets) x d (128)
#pragma unroll
  for (int it = 0; it < 4; ++it) {
    const int task = it * 256 + tid;
    const int c = task >> 7, d = task & 127;
    short8 st;
#pragma unroll
    for (int s2 = 0; s2 < 8; ++s2) st[s2] = vtile[c * 8 + s2][d];
    const int jl = jl0 + c * 8;
    const int kf = jl >> 5, lg2 = (jl >> 3) & 3;
    *(short8*)(V2 + kvoff(t, kf, lg2, d)) = st;
  }
}

// ---------------------------------------------------------------------------
// Kernel 2: fused masked-softmax attention.
// 256 blocks x 1024 threads (16 waves, 1 block/CU, 4 waves/SIMD at <=128 VGPR).
// Wave (ir, wc): i-rows [ir*16,+16), j-slice [wc*32,+32).
// K/V double-buffered in LDS via global_load_lds; one barrier per step;
// softmax fully in-register (swapped QK^T + bpermute exchange).
// ---------------------------------------------------------------------------
__device__ __forceinline__ void stage_kv(char* dst, const char* __restrict__ K3,
                                         const char* __restrict__ V2, int t, int tid) {
  const char* gk = K3 + ((size_t)t << 15);
  const char* gv = V2 + ((size_t)t << 15);
  const int o = tid * 16;
  gload16(dst + o,         gk + o);
  gload16(dst + 16384 + o, gk + 16384 + o);
  gload16(dst + 32768 + o, gv + o);
  gload16(dst + 49152 + o, gv + 16384 + o);
}

__device__ __forceinline__ void load_adj(i32x4 (&a)[2], const int* __restrict__ adj,
                                         int t, int i0, int ir, int wc, int l15, int lg) {
  const int* ap = adj + (size_t)(i0 + ir * 16 + l15) * NTOK + t * 128 + wc * 32 + lg * 4;
  a[0] = *(const i32x4*)ap;
  a[1] = *(const i32x4*)(ap + 16);
}

__device__ __forceinline__ void attn_step(
    int t, const char* cur, char* nxt,
    const char* __restrict__ K3, const char* __restrict__ V2,
    const int* __restrict__ adj,
    const short8 (&qf)[4], f32x4 (&acc)[8], float& dsum,
    const i32x4 (&adjC)[2], i32x4 (&adjN)[2],
    int i0, int ir, int wc, int l15, int lg, int lane, int tid,
    int adA, int adB, bool hi5) {
  const int tn = (t + 1) & (NJT - 1);

  // stage next K/V tile into the other LDS buffer; prefetch next adj to regs
  stage_kv(nxt, K3, V2, tn, tid);
  load_adj(adjN, adj, tn, i0, ir, wc, l15, lg);

  // ---- S^T = K @ Q^T : lane holds S[i=l15][j=(wc*2+jf)*16 + lg*4+r] ----
  f32x4 sT[2];
#pragma unroll
  for (int jf = 0; jf < 2; ++jf) {
    sT[jf][0] = 0.f; sT[jf][1] = 0.f; sT[jf][2] = 0.f; sT[jf][3] = 0.f;
  }
#pragma unroll
  for (int jf = 0; jf < 2; ++jf)
#pragma unroll
    for (int kf = 0; kf < 4; ++kf) {
      const short8 kfr = *(const short8*)(cur + (((wc * 2 + jf) * 4 + kf) << 10) + lane * 16);
      sT[jf] = __builtin_amdgcn_mfma_f32_16x16x32_bf16(kfr, qf[kf], sT[jf], 0, 0, 0);
    }

  // ---- mask + exp2 + row-sum + pack, all in-register ----
  unsigned pk_[2][2];
#pragma unroll
  for (int jf = 0; jf < 2; ++jf) {
    const i32x4 a = adjC[jf];
    const float p0 = __builtin_exp2f(a[0] ? sT[jf][0] : 0.0f);
    const float p1 = __builtin_exp2f(a[1] ? sT[jf][1] : 0.0f);
    const float p2 = __builtin_exp2f(a[2] ? sT[jf][2] : 0.0f);
    const float p3 = __builtin_exp2f(a[3] ? sT[jf][3] : 0.0f);
    dsum += (p0 + p1) + (p2 + p3);
    pk_[jf][0] = pkbf(p0, p1);
    pk_[jf][1] = pkbf(p2, p3);
  }

  // ---- in-wave exchange: build PV A-frag P[i=l15][j=lg*8+e] ----
  i32x4 pa;
#pragma unroll
  for (int w2 = 0; w2 < 4; ++w2) {
    const int addr = (w2 < 2) ? adA : adB;
    const int r0 = __builtin_amdgcn_ds_bpermute(addr, (int)pk_[0][w2 & 1]);
    const int r1 = __builtin_amdgcn_ds_bpermute(addr, (int)pk_[1][w2 & 1]);
    pa[w2] = hi5 ? r1 : r0;
  }
  const short8 pa8 = *(const short8*)&pa;

  // ---- acc += P @ V (this wave's j:32, full d:128) ----
#pragma unroll
  for (int nf = 0; nf < 8; ++nf) {
    const short8 vb = *(const short8*)(cur + 32768 + ((((wc * 4 + lg) * 128) + nf * 16 + l15) << 4));
    acc[nf] = __builtin_amdgcn_mfma_f32_16x16x32_bf16(pa8, vb, acc[nf], 0, 0, 0);
  }

  // vmcnt(0)+lgkmcnt(0)+barrier: stage complete, buffers flip
  __syncthreads();
}

__global__ __launch_bounds__(1024, 4) void attn_kernel(
    const short* __restrict__ QbG, const char* __restrict__ K3,
    const char* __restrict__ V2, const int* __restrict__ adj,
    float* __restrict__ out) {
  __shared__ __align__(16) char kv[2][65536];   // [buf][ K:32KB | V:32KB ]
  __shared__ float denp[4][64];

  const int tid = threadIdx.x;
  const int w = tid >> 6, lane = tid & 63;
  const int l15 = lane & 15, lg = lane >> 4;
  const int ir = w >> 2, wc = w & 3;
  const int i0 = blockIdx.x * RB;

  // bpermute source-lane addresses; jf-select by lane bit 5
  const int adA = 4 * (l15 + 16 * ((lg & 1) * 2));
  const int adB = adA + 64;
  const bool hi5 = (lane & 32) != 0;

  // Q B-frags (persist): lane holds Q[i = i0+ir*16+l15][kf*32+lg*8 ..+8]
  short8 qf[4];
  {
    const int i = i0 + ir * 16 + l15;
#pragma unroll
    for (int kf = 0; kf < 4; ++kf)
      qf[kf] = *(const short8*)(QbG + (size_t)i * DIM + kf * 32 + lg * 8);
  }

  f32x4 acc[8];
#pragma unroll
  for (int nf = 0; nf < 8; ++nf) {
    acc[nf][0] = 0.f; acc[nf][1] = 0.f; acc[nf][2] = 0.f; acc[nf][3] = 0.f;
  }
  float dsum = 0.f;
  i32x4 adjA_[2], adjB_[2];

  stage_kv(kv[0], K3, V2, 0, tid);
  load_adj(adjA_, adj, 0, i0, ir, wc, l15, lg);
  __syncthreads();

  for (int t = 0; t < NJT; t += 2) {
    attn_step(t,     kv[0], kv[1], K3, V2, adj, qf, acc, dsum, adjA_, adjB_,
              i0, ir, wc, l15, lg, lane, tid, adA, adB, hi5);
    attn_step(t + 1, kv[1], kv[0], K3, V2, adj, qf, acc, dsum, adjB_, adjA_,
              i0, ir, wc, l15, lg, lane, tid, adA, adB, hi5);
  }

  // ---- denominator: lane covers i=l15; sum over lg groups, then wc ----
  float d0 = dsum;
  d0 += __shfl_xor(d0, 16);
  d0 += __shfl_xor(d0, 32);
  if (lg == 0) denp[wc][ir * 16 + l15] = d0;

  // ---- cross-wc acc reduction through LDS (reuse staging buffers) ----
  float* red = (float*)kv;   // 12 slots x 16 rows x 132 floats = 99 KB
  if (wc != 0) {
    const int base = ((wc - 1) * 4 + ir) * 16 * 132;
#pragma unroll
    for (int nf = 0; nf < 8; ++nf)
#pragma unroll
      for (int r = 0; r < 4; ++r)
        red[base + (lg * 4 + r) * 132 + nf * 16 + l15] = acc[nf][r];
  }
  __syncthreads();

  if (wc == 0) {
#pragma unroll
    for (int s = 0; s < 3; ++s) {
      const int base = (s * 4 + ir) * 16 * 132;
#pragma unroll
      for (int nf = 0; nf < 8; ++nf)
#pragma unroll
        for (int r = 0; r < 4; ++r)
          acc[nf][r] += red[base + (lg * 4 + r) * 132 + nf * 16 + l15];
    }
    float den[4];
#pragma unroll
    for (int r = 0; r < 4; ++r) {
      const int il = ir * 16 + lg * 4 + r;
      den[r] = (denp[0][il] + denp[1][il]) + (denp[2][il] + denp[3][il]);
    }
#pragma unroll
    for (int nf = 0; nf < 8; ++nf)
#pragma unroll
      for (int r = 0; r < 4; ++r) {
        const int i = ir * 16 + lg * 4 + r;
        out[(size_t)(i0 + i) * DIM + nf * 16 + l15] = acc[nf][r] / den[r];
      }
  }
}

// ---------------------------------------------------------------------------
extern "C" void kernel_launch(void* const* d_in, const int* in_sizes, int n_in,
                              void* d_out, int out_size, void* d_ws, size_t ws_size,
                              hipStream_t stream) {
  const float* X  = (const float*)d_in[0];
  const float* Wq = (const float*)d_in[1];
  const float* bq = (const float*)d_in[2];
  const float* Wk = (const float*)d_in[3];
  const float* bk = (const float*)d_in[4];
  const float* Wv = (const float*)d_in[5];
  const float* bv = (const float*)d_in[6];
  const int*  adj = (const int*)d_in[7];
  float* out = (float*)d_out;

  char* ws = (char*)d_ws;
  short* Qb = (short*)ws;                       // 4 MB bf16 [N][128]
  char*  K3 = ws + ((size_t)4 << 20);           // 4 MB A-frag-contiguous K
  char*  V2 = ws + ((size_t)8 << 20);           // 4 MB B-frag-contiguous V^T

  proj_kernel<<<256, 256, 0, stream>>>(X, Wq, bq, Wk, bk, Wv, bv, Qb, K3, V2);
  attn_kernel<<<256, 1024, 0, stream>>>(Qb, K3, V2, adj, out);
}